// Round 21
// baseline (106.480 us; speedup 1.0000x reference)
//
#include <hip/hip_runtime.h>
#include <hip/hip_fp16.h>

#define H 32
#define TPB 256
#define EPT 16            // edges per thread in place-A (4096 edges per WG, 367 WGs)
#define SLOTS 128         // dst slots per fine bucket (= 64 bridge nodes x 2 relations)
#define CAP 2048          // fine bucket capacity (mean 960, +35 sigma)
#define SUPB 2048         // dst slots per super bucket (16 fine buckets)
#define CAP1 22528        // super capacity (uniform mean 15360, +57 sigma)
#define K2 4              // WGs per super in pass B
#define NSUPMAX 128       // static bound (actual NSUP = 98)

// ---------------- prep: heterogeneous kernel -----------------------------------------
// Blocks [0, encBlocks): encoder (thread = node).
// Blocks [encBlocks, ...): place-A: radix-bin edges into 98 coarse supers.
// Interleaved dst key: key = 2*d (rb, gathers h_r) or 2*d+1 (bb, gathers h_b).
// gcur1 must be zeroed before launch.
__global__ void __launch_bounds__(TPB) prep_kernel(
        // encoder args
        const float* __restrict__ x_b, const float* __restrict__ x_r,
        const float* __restrict__ W_b, const float* __restrict__ b_b,
        const float* __restrict__ W_r, const float* __restrict__ b_r,
        __half* __restrict__ h_b16, __half* __restrict__ h_r16,
        int NB, int NR, int encBlocks,
        // place-A args
        const int* __restrict__ src_rb, const int* __restrict__ dst_rb,
        const int* __restrict__ src_bb, const int* __restrict__ dst_bb,
        int* __restrict__ gcur1, int* __restrict__ bins1,
        int E_RB, int E_BB, int NSUP) {
    int t = threadIdx.x;

    if (blockIdx.x < encBlocks) {
        // ---------------- encoder part ----------------
        __shared__ float sWb[16][H];
        __shared__ float sWr8[8][H];
        __shared__ float sbb[H];
        __shared__ float sbr[H];
        for (int i = t; i < 16 * H; i += TPB) ((float*)sWb)[i] = W_b[i];
        for (int i = t; i < 8 * H; i += TPB) ((float*)sWr8)[i] = W_r[i];
        if (t < H) { sbb[t] = b_b[t]; sbr[t] = b_r[t]; }
        __syncthreads();

        long long node = (long long)blockIdx.x * TPB + t;
        if (node < NB) {
            const float4* px = (const float4*)(x_b + node * 16);
            float acc[H];
            #pragma unroll
            for (int j = 0; j < H; ++j) acc[j] = sbb[j];
            #pragma unroll
            for (int c = 0; c < 4; ++c) {
                float4 q = px[c];
                float xs[4] = {q.x, q.y, q.z, q.w};
                #pragma unroll
                for (int u = 0; u < 4; ++u) {
                    int k = c * 4 + u;
                    #pragma unroll
                    for (int j = 0; j < H; ++j)
                        acc[j] = fmaf(xs[u], sWb[k][j], acc[j]);
                }
            }
            __half2 o[H / 2];
            #pragma unroll
            for (int j2 = 0; j2 < H / 2; ++j2)
                o[j2] = __floats2half2_rn(fmaxf(acc[2 * j2], 0.0f), fmaxf(acc[2 * j2 + 1], 0.0f));
            float4* dst = (float4*)(h_b16 + node * H);
            const float4* src = (const float4*)o;
            dst[0] = src[0]; dst[1] = src[1]; dst[2] = src[2]; dst[3] = src[3];
        } else if (node < (long long)NB + NR) {
            long long m = node - NB;
            const float4* px = (const float4*)(x_r + m * 8);
            float acc[H];
            #pragma unroll
            for (int j = 0; j < H; ++j) acc[j] = sbr[j];
            #pragma unroll
            for (int c = 0; c < 2; ++c) {
                float4 q = px[c];
                float xs[4] = {q.x, q.y, q.z, q.w};
                #pragma unroll
                for (int u = 0; u < 4; ++u) {
                    int k = c * 4 + u;
                    #pragma unroll
                    for (int j = 0; j < H; ++j)
                        acc[j] = fmaf(xs[u], sWr8[k][j], acc[j]);
                }
            }
            __half2 o[H / 2];
            #pragma unroll
            for (int j2 = 0; j2 < H / 2; ++j2)
                o[j2] = __floats2half2_rn(fmaxf(acc[2 * j2], 0.0f), fmaxf(acc[2 * j2 + 1], 0.0f));
            float4* dst = (float4*)(h_r16 + m * H);
            const float4* src = (const float4*)o;
            dst[0] = src[0]; dst[1] = src[1]; dst[2] = src[2]; dst[3] = src[3];
        }
    } else {
        // ---------------- place-A: coarse radix into supers ----------------
        // packed1 = (src << 11) | (key & 2047); meta = (sup<<23)|(loc<<11)|(key&2047)
        __shared__ int lcnt[NSUPMAX];
        __shared__ int wbase[NSUPMAX];
        if (t < NSUPMAX) { lcnt[t] = 0; }
        __syncthreads();

        long long e0 = (long long)(blockIdx.x - encBlocks) * (TPB * EPT);
        long long EA = (long long)E_RB + E_BB;
        long long rb4 = (long long)(E_RB >> 2);
        int meta[EPT];

        // pass 1: histogram + meta (dst only, int4 loads)
        #pragma unroll
        for (int j = 0; j < EPT / 4; ++j) {
            long long i4 = (e0 >> 2) + (long long)j * TPB + t;
            long long eb = i4 << 2;
            int dd[4];
            if (eb + 3 < (long long)E_RB) {
                int4 dv = ((const int4*)dst_rb)[i4];
                dd[0] = 2 * dv.x; dd[1] = 2 * dv.y; dd[2] = 2 * dv.z; dd[3] = 2 * dv.w;
            } else if (eb >= (long long)E_RB && eb + 3 < EA) {
                int4 dv = ((const int4*)dst_bb)[i4 - rb4];
                dd[0] = 2 * dv.x + 1; dd[1] = 2 * dv.y + 1; dd[2] = 2 * dv.z + 1; dd[3] = 2 * dv.w + 1;
            } else {
                #pragma unroll
                for (int u = 0; u < 4; ++u) {
                    long long e = eb + u;
                    dd[u] = (e < E_RB) ? 2 * dst_rb[e]
                                       : (e < EA ? 2 * dst_bb[e - E_RB] + 1 : -1);
                }
            }
            #pragma unroll
            for (int u = 0; u < 4; ++u) {
                if (dd[u] >= 0) {
                    int sup = dd[u] >> 11;
                    int loc = atomicAdd(&lcnt[sup], 1);
                    meta[j * 4 + u] = (sup << 23) | (loc << 11) | (dd[u] & 2047);
                } else meta[j * 4 + u] = -1;
            }
        }
        __syncthreads();

        // flush: one global atomic per (WG, nonempty super)
        if (t < NSUP) {
            int c = lcnt[t];
            wbase[t] = c ? (t * CAP1 + atomicAdd(&gcur1[t * 16], c)) : 0;
        }
        __syncthreads();

        // pass 2: re-read src (coalesced), write packed1 into super bins
        #pragma unroll
        for (int j = 0; j < EPT / 4; ++j) {
            long long i4 = (e0 >> 2) + (long long)j * TPB + t;
            long long eb = i4 << 2;
            int ss[4];
            if (eb + 3 < (long long)E_RB) {
                int4 sv = ((const int4*)src_rb)[i4];
                ss[0] = sv.x; ss[1] = sv.y; ss[2] = sv.z; ss[3] = sv.w;
            } else if (eb >= (long long)E_RB && eb + 3 < EA) {
                int4 sv = ((const int4*)src_bb)[i4 - rb4];
                ss[0] = sv.x; ss[1] = sv.y; ss[2] = sv.z; ss[3] = sv.w;
            } else {
                #pragma unroll
                for (int u = 0; u < 4; ++u) {
                    long long e = eb + u;
                    ss[u] = (e < E_RB) ? src_rb[e] : (e < EA ? (int)src_bb[e - E_RB] : 0);
                }
            }
            #pragma unroll
            for (int u = 0; u < 4; ++u) {
                int m = meta[j * 4 + u];
                if (m >= 0) {
                    int sup = (unsigned)m >> 23;
                    int loc = (m >> 11) & 0xFFF;
                    int gslot = wbase[sup] + loc;
                    if (gslot < (sup + 1) * CAP1)        // overflow guard (never fires)
                        bins1[gslot] = (ss[u] << 11) | (m & 2047);
                }
            }
        }
    }
}

// ---------------- place-B: fine radix within each super (coalesced) ------------------
__global__ void __launch_bounds__(TPB) placeB_kernel(
        const int* __restrict__ bins1, const int* __restrict__ gcur1,
        int* __restrict__ gcur2, int* __restrict__ bins, int NBUCK) {
    __shared__ int lcnt[16];
    __shared__ int wbase[16];
    __shared__ int lcur[16];
    int t = threadIdx.x;
    int sup = blockIdx.x / K2;
    int j   = blockIdx.x % K2;
    int n = gcur1[sup * 16];
    if (n > CAP1) n = CAP1;
    int chunk = (n + K2 - 1) / K2;
    int lo = j * chunk;
    int hi = lo + chunk; if (hi > n) hi = n;

    if (t < 16) lcnt[t] = 0;
    __syncthreads();

    const int* __restrict__ seg = bins1 + (long long)sup * CAP1;
    for (int i = lo + t; i < hi; i += TPB)
        atomicAdd(&lcnt[(seg[i] >> 7) & 15], 1);
    __syncthreads();

    if (t < 16) {
        int c = lcnt[t];
        int fb = sup * 16 + t;
        wbase[t] = (c && fb < NBUCK) ? (fb * CAP + atomicAdd(&gcur2[fb * 16], c)) : 0;
        lcur[t] = 0;
    }
    __syncthreads();

    for (int i = lo + t; i < hi; i += TPB) {
        int p = seg[i];
        int f = (p >> 7) & 15;
        int loc = atomicAdd(&lcur[f], 1);
        int fb = sup * 16 + f;
        int gslot = wbase[f] + loc;
        if (gslot < (fb + 1) * CAP)              // overflow guard (never fires)
            bins[gslot] = ((p >> 11) << 7) | (p & 127);
    }
}

// ---------------- fused build+gather+head ------------------------------------------
// Phases A-D as before (interleaved slots: even=rb from h_r, odd=bb from h_b).
// Phase E: head for the bucket's 64 bridge nodes (weights via uniform/scalar loads).
__global__ void __launch_bounds__(TPB) buildgather_kernel(
        const __half* __restrict__ h_r16, const __half* __restrict__ h_b16,
        const int* __restrict__ bins, const int* __restrict__ gcur2,
        __half* __restrict__ mean16, int NB, int N2,
        const float* __restrict__ Wl_rb, const float* __restrict__ bl_rb,
        const float* __restrict__ Wl_bb, const float* __restrict__ bl_bb,
        const float* __restrict__ Wr_rb, const float* __restrict__ Wr_bb,
        const float* __restrict__ Wo, const float* __restrict__ bo,
        float* __restrict__ y) {
    __shared__ int rawbuf[CAP];          // 8 KB
    __shared__ int srcbuf[CAP];          // 8 KB
    __shared__ int lcnt[SLOTS];
    __shared__ int lbase[SLOTS];
    __shared__ int lcur[SLOTS];
    __shared__ int tmp[SLOTS];
    int t = threadIdx.x;
    int b = blockIdx.x;
    int start = b * CAP;
    int n = gcur2[b * 16];
    if (n > CAP) n = CAP;

    if (t < SLOTS) lcnt[t] = 0;
    __syncthreads();

    // phase A: int4 read of bins into LDS + per-slot histogram
    {
        int n4 = n >> 2;
        const int4* bins4 = (const int4*)(bins + start);
        for (int i = t; i < n4; i += TPB) {
            int4 p = bins4[i];
            ((int4*)rawbuf)[i] = p;
            atomicAdd(&lcnt[p.x & 127], 1);
            atomicAdd(&lcnt[p.y & 127], 1);
            atomicAdd(&lcnt[p.z & 127], 1);
            atomicAdd(&lcnt[p.w & 127], 1);
        }
        for (int i = (n4 << 2) + t; i < n; i += TPB) {
            int packed = bins[start + i];
            rawbuf[i] = packed;
            atomicAdd(&lcnt[packed & 127], 1);
        }
    }
    __syncthreads();

    // phase B: exclusive scan of 128 slot counters
    if (t < SLOTS) tmp[t] = lcnt[t];
    __syncthreads();
    for (int off = 1; off < SLOTS; off <<= 1) {
        int x = (t >= off && t < SLOTS) ? tmp[t - off] : 0;
        __syncthreads();
        if (t < SLOTS) tmp[t] += x;
        __syncthreads();
    }
    if (t < SLOTS) { lbase[t] = tmp[t] - lcnt[t]; lcur[t] = tmp[t] - lcnt[t]; }
    __syncthreads();

    // phase C: LDS->LDS scatter, slot-sorted
    for (int i = t; i < n; i += TPB) {
        int packed = rawbuf[i];
        int slot = atomicAdd(&lcur[packed & 127], 1);
        srcbuf[slot] = packed >> 7;
    }
    __syncthreads();

    // phase D: gather; 16 groups of 16 lanes; lane owns channels {2l,2l+1}; 8/4/1 ILP
    int lane = t & 15, g = t >> 4;
    long long base_slot = (long long)b << 7;
    for (int sl = g; sl < SLOTS; sl += (TPB / 16)) {
        long long gd = base_slot + sl;
        if (gd >= N2) break;
        const __half* __restrict__ hs = (gd & 1) ? h_b16 : h_r16;
        int off = lbase[sl];
        int cnt = lcnt[sl];
        float ax = 0.0f, ay = 0.0f;
        int k = 0;
        for (; k + 8 <= cnt; k += 8) {
            int s[8];
            #pragma unroll
            for (int jj = 0; jj < 8; ++jj) s[jj] = srcbuf[off + k + jj];
            float2 f[8];
            #pragma unroll
            for (int jj = 0; jj < 8; ++jj)
                f[jj] = __half22float2(*(const __half2*)(hs + (long long)s[jj] * H + 2 * lane));
            #pragma unroll
            for (int jj = 0; jj < 8; ++jj) { ax += f[jj].x; ay += f[jj].y; }
        }
        if (k + 4 <= cnt) {
            int s[4];
            #pragma unroll
            for (int jj = 0; jj < 4; ++jj) s[jj] = srcbuf[off + k + jj];
            float2 f[4];
            #pragma unroll
            for (int jj = 0; jj < 4; ++jj)
                f[jj] = __half22float2(*(const __half2*)(hs + (long long)s[jj] * H + 2 * lane));
            #pragma unroll
            for (int jj = 0; jj < 4; ++jj) { ax += f[jj].x; ay += f[jj].y; }
            k += 4;
        }
        for (; k < cnt; ++k) {
            int s = srcbuf[off + k];
            float2 f = __half22float2(*(const __half2*)(hs + (long long)s * H + 2 * lane));
            ax += f.x; ay += f.y;
        }
        float inv = 1.0f / fmaxf((float)cnt, 1.0f);
        *(__half2*)(mean16 + gd * H + 2 * lane) = __floats2half2_rn(ax * inv, ay * inv);
    }

    __threadfence_block();
    __syncthreads();

    // phase E: head for this bucket's 64 bridge nodes (thread t < 64 owns node b*64+t)
    if (t < 64) {
        int node = b * 64 + t;
        if (node < NB) {
            // mean16 rows 2*node (rb) and 2*node+1 (bb) are contiguous: 128 B
            const float4* pm = (const float4*)(mean16 + (long long)(2 * node) * H);
            const float4* ph = (const float4*)(h_b16 + (long long)node * H);

            float acc[H];
            #pragma unroll
            for (int j = 0; j < H; ++j) acc[j] = bl_rb[j] + bl_bb[j];

            #pragma unroll
            for (int c = 0; c < 4; ++c) {            // 8 k-values per chunk
                float4 qr = pm[c];
                float4 qb = pm[4 + c];
                float4 qh = ph[c];
                const __half2* hr = (const __half2*)&qr;
                const __half2* hb = (const __half2*)&qb;
                const __half2* hh = (const __half2*)&qh;
                #pragma unroll
                for (int u = 0; u < 4; ++u) {
                    float2 fr = __half22float2(hr[u]);
                    float2 fb = __half22float2(hb[u]);
                    float2 fh = __half22float2(hh[u]);
                    int k0 = c * 8 + u * 2;
                    #pragma unroll
                    for (int j = 0; j < H; ++j) {
                        acc[j] = fmaf(fr.x, Wl_rb[k0 * H + j], acc[j]);
                        acc[j] = fmaf(fb.x, Wl_bb[k0 * H + j], acc[j]);
                        acc[j] = fmaf(fh.x, Wr_rb[k0 * H + j] + Wr_bb[k0 * H + j], acc[j]);
                        acc[j] = fmaf(fr.y, Wl_rb[(k0 + 1) * H + j], acc[j]);
                        acc[j] = fmaf(fb.y, Wl_bb[(k0 + 1) * H + j], acc[j]);
                        acc[j] = fmaf(fh.y, Wr_rb[(k0 + 1) * H + j] + Wr_bb[(k0 + 1) * H + j], acc[j]);
                    }
                }
            }

            float out = 0.0f;
            #pragma unroll
            for (int j = 0; j < H; ++j)
                out = fmaf(fmaxf(acc[j], 0.0f), Wo[j], out);
            y[node] = out + bo[0];
        }
    }
}

extern "C" void kernel_launch(void* const* d_in, const int* in_sizes, int n_in,
                              void* d_out, int out_size, void* d_ws, size_t ws_size,
                              hipStream_t stream) {
    const float* x_bridge = (const float*)d_in[0];
    const float* x_road   = (const float*)d_in[1];
    const int* src_rb = (const int*)d_in[4];
    const int* dst_rb = (const int*)d_in[5];
    const int* src_bb = (const int*)d_in[6];
    const int* dst_bb = (const int*)d_in[7];
    const float* W_enc_b = (const float*)d_in[8];
    const float* b_enc_b = (const float*)d_in[9];
    const float* W_enc_r = (const float*)d_in[10];
    const float* b_enc_r = (const float*)d_in[11];
    const float* Wl_rb = (const float*)d_in[15];
    const float* bl_rb = (const float*)d_in[16];
    const float* Wr_rb = (const float*)d_in[17];
    const float* Wl_bb = (const float*)d_in[18];
    const float* bl_bb = (const float*)d_in[19];
    const float* Wr_bb = (const float*)d_in[20];
    const float* Wo = (const float*)d_in[21];
    const float* bo = (const float*)d_in[22];
    float* y = (float*)d_out;

    const int NB = in_sizes[0] / 16;
    const int NR = in_sizes[1] / 8;
    const int E_RB = in_sizes[4];
    const int E_BB = in_sizes[6];
    const int N2 = 2 * NB;
    const long long E_ALL = (long long)E_RB + E_BB;
    const int NBUCK = (N2 + SLOTS - 1) / SLOTS;     // 1563
    const int NSUP  = (N2 + SUPB - 1) / SUPB;       // 98

    // Workspace layout (~56 MB)
    char* wp = (char*)d_ws;
    __half* h_r16  = (__half*)wp; wp += (size_t)NR * H * sizeof(__half);
    __half* h_b16  = (__half*)wp; wp += (size_t)NB * H * sizeof(__half);
    __half* mean16 = (__half*)wp; wp += (size_t)N2 * H * sizeof(__half);
    int* bins1 = (int*)wp;       wp += (size_t)NSUP * CAP1 * sizeof(int);
    int* bins  = (int*)wp;       wp += (size_t)NBUCK * CAP * sizeof(int);
    int* gcur1 = (int*)wp;       wp += (size_t)NSUP * 16 * sizeof(int);
    int* gcur2 = (int*)wp;       wp += (size_t)NBUCK * 16 * sizeof(int);

    // zero both cursor arrays (contiguous)
    hipMemsetAsync(gcur1, 0, (size_t)(NSUP + NBUCK) * 16 * sizeof(int), stream);

    long long nodes = (long long)NB + NR;
    int encBlocks = (int)((nodes + TPB - 1) / TPB);                      // 1172
    int placeBlocks = (int)((E_ALL + (TPB * EPT) - 1) / (TPB * EPT));    // 367
    prep_kernel<<<encBlocks + placeBlocks, TPB, 0, stream>>>(
        x_bridge, x_road, W_enc_b, b_enc_b, W_enc_r, b_enc_r,
        h_b16, h_r16, NB, NR, encBlocks,
        src_rb, dst_rb, src_bb, dst_bb, gcur1, bins1, E_RB, E_BB, NSUP);

    // fine radix within supers (coalesced writes)
    placeB_kernel<<<NSUP * K2, TPB, 0, stream>>>(bins1, gcur1, gcur2, bins, NBUCK);

    // fused per-bucket slot-sort + gather + head -> y
    buildgather_kernel<<<NBUCK, TPB, 0, stream>>>(h_r16, h_b16, bins, gcur2,
                                                  mean16, NB, N2,
                                                  Wl_rb, bl_rb, Wl_bb, bl_bb,
                                                  Wr_rb, Wr_bb, Wo, bo, y);
}

// Round 22
// 100.062 us; speedup vs baseline: 1.0641x; 1.0641x over previous
//
#include <hip/hip_runtime.h>
#include <hip/hip_fp16.h>

#define H 32
#define TPB 256
#define EPT 8             // edges per thread in place-A (2048 edges per WG, 733 WGs)
#define SLOTS 128         // dst slots per fine bucket
#define CAP 2048          // fine bucket capacity (rb-region mean 1280, +21 sigma)
#define SUPB 2048         // dst slots per super bucket (16 fine buckets)
#define CAP1 22528        // super capacity (rb-region mean 20480, +14 sigma)
#define K2 4              // WGs per super in pass B
#define NSUPMAX 128       // static bound (actual NSUP = 98)

// ---------------- prep: heterogeneous kernel -----------------------------------------
// Blocks [0, encBlocks): encoder (thread = node).
// Blocks [encBlocks, ...): place-A: radix-bin edges into 98 coarse supers.
// gcur1 must be zeroed before launch.
__global__ void __launch_bounds__(TPB) prep_kernel(
        // encoder args
        const float* __restrict__ x_b, const float* __restrict__ x_r,
        const float* __restrict__ W_b, const float* __restrict__ b_b,
        const float* __restrict__ W_r, const float* __restrict__ b_r,
        __half* __restrict__ h_b16, __half* __restrict__ h_r16,
        int NB, int NR, int encBlocks,
        // place-A args
        const int* __restrict__ src_rb, const int* __restrict__ dst_rb,
        const int* __restrict__ src_bb, const int* __restrict__ dst_bb,
        int* __restrict__ gcur1, int* __restrict__ bins1,
        int E_RB, int E_BB, int NSUP) {
    int t = threadIdx.x;

    if (blockIdx.x < encBlocks) {
        // ---------------- encoder part ----------------
        __shared__ float sWb[16][H];
        __shared__ float sWr8[8][H];
        __shared__ float sbb[H];
        __shared__ float sbr[H];
        for (int i = t; i < 16 * H; i += TPB) ((float*)sWb)[i] = W_b[i];
        for (int i = t; i < 8 * H; i += TPB) ((float*)sWr8)[i] = W_r[i];
        if (t < H) { sbb[t] = b_b[t]; sbr[t] = b_r[t]; }
        __syncthreads();

        long long node = (long long)blockIdx.x * TPB + t;
        if (node < NB) {
            const float4* px = (const float4*)(x_b + node * 16);
            float acc[H];
            #pragma unroll
            for (int j = 0; j < H; ++j) acc[j] = sbb[j];
            #pragma unroll
            for (int c = 0; c < 4; ++c) {
                float4 q = px[c];
                float xs[4] = {q.x, q.y, q.z, q.w};
                #pragma unroll
                for (int u = 0; u < 4; ++u) {
                    int k = c * 4 + u;
                    #pragma unroll
                    for (int j = 0; j < H; ++j)
                        acc[j] = fmaf(xs[u], sWb[k][j], acc[j]);
                }
            }
            __half2 o[H / 2];
            #pragma unroll
            for (int j2 = 0; j2 < H / 2; ++j2)
                o[j2] = __floats2half2_rn(fmaxf(acc[2 * j2], 0.0f), fmaxf(acc[2 * j2 + 1], 0.0f));
            float4* dst = (float4*)(h_b16 + node * H);
            const float4* src = (const float4*)o;
            dst[0] = src[0]; dst[1] = src[1]; dst[2] = src[2]; dst[3] = src[3];
        } else if (node < (long long)NB + NR) {
            long long m = node - NB;
            const float4* px = (const float4*)(x_r + m * 8);
            float acc[H];
            #pragma unroll
            for (int j = 0; j < H; ++j) acc[j] = sbr[j];
            #pragma unroll
            for (int c = 0; c < 2; ++c) {
                float4 q = px[c];
                float xs[4] = {q.x, q.y, q.z, q.w};
                #pragma unroll
                for (int u = 0; u < 4; ++u) {
                    int k = c * 4 + u;
                    #pragma unroll
                    for (int j = 0; j < H; ++j)
                        acc[j] = fmaf(xs[u], sWr8[k][j], acc[j]);
                }
            }
            __half2 o[H / 2];
            #pragma unroll
            for (int j2 = 0; j2 < H / 2; ++j2)
                o[j2] = __floats2half2_rn(fmaxf(acc[2 * j2], 0.0f), fmaxf(acc[2 * j2 + 1], 0.0f));
            float4* dst = (float4*)(h_r16 + m * H);
            const float4* src = (const float4*)o;
            dst[0] = src[0]; dst[1] = src[1]; dst[2] = src[2]; dst[3] = src[3];
        }
    } else {
        // ---------------- place-A: coarse radix into supers ----------------
        // packed1 = (src << 11) | (d & 2047); meta = (sup<<23)|(loc<<11)|(d&2047)
        __shared__ int lcnt[NSUPMAX];
        __shared__ int wbase[NSUPMAX];
        if (t < NSUPMAX) { lcnt[t] = 0; }
        __syncthreads();

        long long e0 = (long long)(blockIdx.x - encBlocks) * (TPB * EPT);
        long long EA = (long long)E_RB + E_BB;
        long long rb4 = (long long)(E_RB >> 2);
        int meta[EPT];

        // pass 1: histogram + meta (dst only, int4 loads)
        #pragma unroll
        for (int j = 0; j < EPT / 4; ++j) {
            long long i4 = (e0 >> 2) + (long long)j * TPB + t;
            long long eb = i4 << 2;
            int dd[4];
            if (eb + 3 < (long long)E_RB) {
                int4 dv = ((const int4*)dst_rb)[i4];
                dd[0] = dv.x; dd[1] = dv.y; dd[2] = dv.z; dd[3] = dv.w;
            } else if (eb >= (long long)E_RB && eb + 3 < EA) {
                int4 dv = ((const int4*)dst_bb)[i4 - rb4];
                dd[0] = dv.x + NB; dd[1] = dv.y + NB; dd[2] = dv.z + NB; dd[3] = dv.w + NB;
            } else {
                #pragma unroll
                for (int u = 0; u < 4; ++u) {
                    long long e = eb + u;
                    dd[u] = (e < E_RB) ? dst_rb[e] : (e < EA ? NB + dst_bb[e - E_RB] : -1);
                }
            }
            #pragma unroll
            for (int u = 0; u < 4; ++u) {
                if (dd[u] >= 0) {
                    int sup = dd[u] >> 11;
                    int loc = atomicAdd(&lcnt[sup], 1);
                    meta[j * 4 + u] = (sup << 23) | (loc << 11) | (dd[u] & 2047);
                } else meta[j * 4 + u] = -1;
            }
        }
        __syncthreads();

        // flush: one global atomic per (WG, nonempty super)
        if (t < NSUP) {
            int c = lcnt[t];
            wbase[t] = c ? (t * CAP1 + atomicAdd(&gcur1[t * 16], c)) : 0;
        }
        __syncthreads();

        // pass 2: re-read src (coalesced), write packed1 into super bins
        #pragma unroll
        for (int j = 0; j < EPT / 4; ++j) {
            long long i4 = (e0 >> 2) + (long long)j * TPB + t;
            long long eb = i4 << 2;
            int ss[4];
            if (eb + 3 < (long long)E_RB) {
                int4 sv = ((const int4*)src_rb)[i4];
                ss[0] = sv.x; ss[1] = sv.y; ss[2] = sv.z; ss[3] = sv.w;
            } else if (eb >= (long long)E_RB && eb + 3 < EA) {
                int4 sv = ((const int4*)src_bb)[i4 - rb4];
                ss[0] = sv.x; ss[1] = sv.y; ss[2] = sv.z; ss[3] = sv.w;
            } else {
                #pragma unroll
                for (int u = 0; u < 4; ++u) {
                    long long e = eb + u;
                    ss[u] = (e < E_RB) ? src_rb[e] : (e < EA ? (int)src_bb[e - E_RB] : 0);
                }
            }
            #pragma unroll
            for (int u = 0; u < 4; ++u) {
                int m = meta[j * 4 + u];
                if (m >= 0) {
                    int sup = (unsigned)m >> 23;
                    int loc = (m >> 11) & 0xFFF;
                    int gslot = wbase[sup] + loc;
                    if (gslot < (sup + 1) * CAP1)        // overflow guard (never fires)
                        bins1[gslot] = (ss[u] << 11) | (m & 2047);
                }
            }
        }
    }
}

// ---------------- place-B: fine radix within each super (coalesced) ------------------
// K2 WGs per super; each sub-bins its chunk into the super's 16 fine buckets.
__global__ void __launch_bounds__(TPB) placeB_kernel(
        const int* __restrict__ bins1, const int* __restrict__ gcur1,
        int* __restrict__ gcur2, int* __restrict__ bins, int NBUCK) {
    __shared__ int lcnt[16];
    __shared__ int wbase[16];
    __shared__ int lcur[16];
    int t = threadIdx.x;
    int sup = blockIdx.x / K2;
    int j   = blockIdx.x % K2;
    int n = gcur1[sup * 16];
    if (n > CAP1) n = CAP1;
    int chunk = (n + K2 - 1) / K2;
    int lo = j * chunk;
    int hi = lo + chunk; if (hi > n) hi = n;

    if (t < 16) lcnt[t] = 0;
    __syncthreads();

    const int* __restrict__ seg = bins1 + (long long)sup * CAP1;
    // pass 1: histogram over 16 fine buckets
    for (int i = lo + t; i < hi; i += TPB)
        atomicAdd(&lcnt[(seg[i] >> 7) & 15], 1);
    __syncthreads();

    if (t < 16) {
        int c = lcnt[t];
        int fb = sup * 16 + t;
        wbase[t] = (c && fb < NBUCK) ? (fb * CAP + atomicAdd(&gcur2[fb * 16], c)) : 0;
        lcur[t] = 0;
    }
    __syncthreads();

    // pass 2: re-read (L2-hot), scatter into fine bins (long runs -> coalesced)
    for (int i = lo + t; i < hi; i += TPB) {
        int p = seg[i];
        int f = (p >> 7) & 15;
        int loc = atomicAdd(&lcur[f], 1);
        int fb = sup * 16 + f;
        int gslot = wbase[f] + loc;
        if (gslot < (fb + 1) * CAP)              // overflow guard (never fires)
            bins[gslot] = ((p >> 11) << 7) | (p & 127);
    }
}

// ---------------- fused build+gather: int4 bins read, sort, unroll-8 gather ----------
__global__ void __launch_bounds__(TPB) buildgather_kernel(
        const __half* __restrict__ h_r16, const __half* __restrict__ h_b16,
        const int* __restrict__ bins, const int* __restrict__ gcur2,
        __half* __restrict__ mean16, int NB, int N2) {
    __shared__ int rawbuf[CAP];          // 8 KB
    __shared__ int srcbuf[CAP];          // 8 KB
    __shared__ int lcnt[SLOTS];
    __shared__ int lbase[SLOTS];
    __shared__ int lcur[SLOTS];
    __shared__ int tmp[SLOTS];
    int t = threadIdx.x;
    int b = blockIdx.x;
    int start = b * CAP;
    int n = gcur2[b * 16];
    if (n > CAP) n = CAP;

    if (t < SLOTS) lcnt[t] = 0;
    __syncthreads();

    // phase A: int4 read of bins into LDS + per-slot histogram
    {
        int n4 = n >> 2;
        const int4* bins4 = (const int4*)(bins + start);
        for (int i = t; i < n4; i += TPB) {
            int4 p = bins4[i];
            ((int4*)rawbuf)[i] = p;
            atomicAdd(&lcnt[p.x & 127], 1);
            atomicAdd(&lcnt[p.y & 127], 1);
            atomicAdd(&lcnt[p.z & 127], 1);
            atomicAdd(&lcnt[p.w & 127], 1);
        }
        for (int i = (n4 << 2) + t; i < n; i += TPB) {
            int packed = bins[start + i];
            rawbuf[i] = packed;
            atomicAdd(&lcnt[packed & 127], 1);
        }
    }
    __syncthreads();

    // phase B: exclusive scan of 128 slot counters
    if (t < SLOTS) tmp[t] = lcnt[t];
    __syncthreads();
    for (int off = 1; off < SLOTS; off <<= 1) {
        int x = (t >= off && t < SLOTS) ? tmp[t - off] : 0;
        __syncthreads();
        if (t < SLOTS) tmp[t] += x;
        __syncthreads();
    }
    if (t < SLOTS) { lbase[t] = tmp[t] - lcnt[t]; lcur[t] = tmp[t] - lcnt[t]; }
    __syncthreads();

    // phase C: LDS->LDS scatter, slot-sorted
    for (int i = t; i < n; i += TPB) {
        int packed = rawbuf[i];
        int slot = atomicAdd(&lcur[packed & 127], 1);
        srcbuf[slot] = packed >> 7;
    }
    __syncthreads();

    // phase D: gather; 16 groups of 16 lanes; lane owns channels {2l,2l+1}; 8/4/1 ILP
    int lane = t & 15, g = t >> 4;
    long long base_slot = (long long)b << 7;
    for (int sl = g; sl < SLOTS; sl += (TPB / 16)) {
        long long gd = base_slot + sl;
        if (gd >= N2) break;
        const __half* __restrict__ hs = (gd < NB) ? h_r16 : h_b16;
        int off = lbase[sl];
        int cnt = lcnt[sl];
        float ax = 0.0f, ay = 0.0f;
        int k = 0;
        for (; k + 8 <= cnt; k += 8) {
            int s[8];
            #pragma unroll
            for (int jj = 0; jj < 8; ++jj) s[jj] = srcbuf[off + k + jj];
            float2 f[8];
            #pragma unroll
            for (int jj = 0; jj < 8; ++jj)
                f[jj] = __half22float2(*(const __half2*)(hs + (long long)s[jj] * H + 2 * lane));
            #pragma unroll
            for (int jj = 0; jj < 8; ++jj) { ax += f[jj].x; ay += f[jj].y; }
        }
        if (k + 4 <= cnt) {
            int s[4];
            #pragma unroll
            for (int jj = 0; jj < 4; ++jj) s[jj] = srcbuf[off + k + jj];
            float2 f[4];
            #pragma unroll
            for (int jj = 0; jj < 4; ++jj)
                f[jj] = __half22float2(*(const __half2*)(hs + (long long)s[jj] * H + 2 * lane));
            #pragma unroll
            for (int jj = 0; jj < 4; ++jj) { ax += f[jj].x; ay += f[jj].y; }
            k += 4;
        }
        for (; k < cnt; ++k) {
            int s = srcbuf[off + k];
            float2 f = __half22float2(*(const __half2*)(hs + (long long)s * H + 2 * lane));
            ax += f.x; ay += f.y;
        }
        float inv = 1.0f / fmaxf((float)cnt, 1.0f);
        *(__half2*)(mean16 + gd * H + 2 * lane) = __floats2half2_rn(ax * inv, ay * inv);
    }
}

// ---------------- fused head (thread = node, fp16 inputs, W broadcast from LDS) ----------
__global__ void __launch_bounds__(TPB) head_kernel(
        const __half* __restrict__ h_b16,
        const __half* __restrict__ mean16,   // [2NB, H]
        const float* __restrict__ Wl_rb,
        const float* __restrict__ bl_rb,
        const float* __restrict__ Wl_bb,
        const float* __restrict__ bl_bb,
        const float* __restrict__ Wr_rb,
        const float* __restrict__ Wr_bb,
        const float* __restrict__ Wo,
        const float* __restrict__ bo,
        float* __restrict__ y, int N) {
    __shared__ float sWl_rb[H][H];
    __shared__ float sWl_bb[H][H];
    __shared__ float sWr[H][H];
    __shared__ float sbl[H];
    __shared__ float sWo[H];
    __shared__ float sbo;

    int t = threadIdx.x;
    for (int i = t; i < H * H; i += blockDim.x) {
        ((float*)sWl_rb)[i] = Wl_rb[i];
        ((float*)sWl_bb)[i] = Wl_bb[i];
        ((float*)sWr)[i]    = Wr_rb[i] + Wr_bb[i];
    }
    if (t < H) {
        sbl[t] = bl_rb[t] + bl_bb[t];
        sWo[t] = Wo[t];
    }
    if (t == 0) sbo = bo[0];
    __syncthreads();

    int node = blockIdx.x * TPB + t;
    if (node >= N) return;

    const float4* pr = (const float4*)(mean16 + (long long)node * H);
    const float4* pb = (const float4*)(mean16 + ((long long)N + node) * H);
    const float4* ph = (const float4*)(h_b16 + (long long)node * H);

    float acc[H];
    #pragma unroll
    for (int j = 0; j < H; ++j) acc[j] = sbl[j];

    #pragma unroll
    for (int c = 0; c < 4; ++c) {            // 8 k-values per chunk
        float4 qr = pr[c];
        float4 qb = pb[c];
        float4 qh = ph[c];
        const __half2* hr = (const __half2*)&qr;
        const __half2* hb = (const __half2*)&qb;
        const __half2* hh = (const __half2*)&qh;
        #pragma unroll
        for (int u = 0; u < 4; ++u) {
            float2 fr = __half22float2(hr[u]);
            float2 fb = __half22float2(hb[u]);
            float2 fh = __half22float2(hh[u]);
            int k0 = c * 8 + u * 2;
            #pragma unroll
            for (int j = 0; j < H; ++j) {
                acc[j] = fmaf(fr.x, sWl_rb[k0][j], acc[j]);
                acc[j] = fmaf(fb.x, sWl_bb[k0][j], acc[j]);
                acc[j] = fmaf(fh.x, sWr[k0][j], acc[j]);
                acc[j] = fmaf(fr.y, sWl_rb[k0 + 1][j], acc[j]);
                acc[j] = fmaf(fb.y, sWl_bb[k0 + 1][j], acc[j]);
                acc[j] = fmaf(fh.y, sWr[k0 + 1][j], acc[j]);
            }
        }
    }

    float out = 0.0f;
    #pragma unroll
    for (int j = 0; j < H; ++j)
        out = fmaf(fmaxf(acc[j], 0.0f), sWo[j], out);
    y[node] = out + sbo;
}

extern "C" void kernel_launch(void* const* d_in, const int* in_sizes, int n_in,
                              void* d_out, int out_size, void* d_ws, size_t ws_size,
                              hipStream_t stream) {
    const float* x_bridge = (const float*)d_in[0];
    const float* x_road   = (const float*)d_in[1];
    const int* src_rb = (const int*)d_in[4];
    const int* dst_rb = (const int*)d_in[5];
    const int* src_bb = (const int*)d_in[6];
    const int* dst_bb = (const int*)d_in[7];
    const float* W_enc_b = (const float*)d_in[8];
    const float* b_enc_b = (const float*)d_in[9];
    const float* W_enc_r = (const float*)d_in[10];
    const float* b_enc_r = (const float*)d_in[11];
    const float* Wl_rb = (const float*)d_in[15];
    const float* bl_rb = (const float*)d_in[16];
    const float* Wr_rb = (const float*)d_in[17];
    const float* Wl_bb = (const float*)d_in[18];
    const float* bl_bb = (const float*)d_in[19];
    const float* Wr_bb = (const float*)d_in[20];
    const float* Wo = (const float*)d_in[21];
    const float* bo = (const float*)d_in[22];
    float* y = (float*)d_out;

    const int NB = in_sizes[0] / 16;
    const int NR = in_sizes[1] / 8;
    const int E_RB = in_sizes[4];
    const int E_BB = in_sizes[6];
    const int N2 = 2 * NB;
    const long long E_ALL = (long long)E_RB + E_BB;
    const int NBUCK = (N2 + SLOTS - 1) / SLOTS;     // 1563
    const int NSUP  = (N2 + SUPB - 1) / SUPB;       // 98

    // Workspace layout (~56 MB)
    char* wp = (char*)d_ws;
    __half* h_r16  = (__half*)wp; wp += (size_t)NR * H * sizeof(__half);
    __half* h_b16  = (__half*)wp; wp += (size_t)NB * H * sizeof(__half);
    __half* mean16 = (__half*)wp; wp += (size_t)N2 * H * sizeof(__half);
    int* bins1 = (int*)wp;       wp += (size_t)NSUP * CAP1 * sizeof(int);
    int* bins  = (int*)wp;       wp += (size_t)NBUCK * CAP * sizeof(int);
    int* gcur1 = (int*)wp;       wp += (size_t)NSUP * 16 * sizeof(int);
    int* gcur2 = (int*)wp;       wp += (size_t)NBUCK * 16 * sizeof(int);

    // zero both cursor arrays (contiguous)
    hipMemsetAsync(gcur1, 0, (size_t)(NSUP + NBUCK) * 16 * sizeof(int), stream);

    long long nodes = (long long)NB + NR;
    int encBlocks = (int)((nodes + TPB - 1) / TPB);                      // 1172
    int placeBlocks = (int)((E_ALL + (TPB * EPT) - 1) / (TPB * EPT));    // 733
    prep_kernel<<<encBlocks + placeBlocks, TPB, 0, stream>>>(
        x_bridge, x_road, W_enc_b, b_enc_b, W_enc_r, b_enc_r,
        h_b16, h_r16, NB, NR, encBlocks,
        src_rb, dst_rb, src_bb, dst_bb, gcur1, bins1, E_RB, E_BB, NSUP);

    // fine radix within supers (coalesced writes)
    placeB_kernel<<<NSUP * K2, TPB, 0, stream>>>(bins1, gcur1, gcur2, bins, NBUCK);

    // fused per-bucket slot-sort (LDS) + gather -> mean16
    buildgather_kernel<<<NBUCK, TPB, 0, stream>>>(h_r16, h_b16, bins, gcur2,
                                                  mean16, NB, N2);

    // fused head
    head_kernel<<<(NB + TPB - 1) / TPB, TPB, 0, stream>>>(h_b16, mean16,
                                                  Wl_rb, bl_rb, Wl_bb, bl_bb,
                                                  Wr_rb, Wr_bb, Wo, bo, y, NB);
}

// Round 23
// 89.372 us; speedup vs baseline: 1.1914x; 1.1196x over previous
//
#include <hip/hip_runtime.h>
#include <hip/hip_fp16.h>

#define H 32
#define TPB 256
#define EPT 16            // edges per thread in place-A (4096 edges per WG, 367 WGs)
#define SLOTS 128         // dst slots per fine bucket
#define CAP 2048          // fine bucket capacity (rb-region mean 1280, +21 sigma)
#define SUPB 2048         // dst slots per super bucket (16 fine buckets)
#define CAP1 22528        // super capacity (rb-region mean 20480, +14 sigma)
#define K2 8              // WGs per super in pass B (784 WGs)
#define NSUPMAX 128       // static bound (actual NSUP = 98)

// ---------------- prep: heterogeneous kernel -----------------------------------------
// Blocks [0, encBlocks): encoder (thread = node).
// Blocks [encBlocks, ...): place-A: radix-bin edges into 98 coarse supers.
// gcur1 must be zeroed before launch.
__global__ void __launch_bounds__(TPB) prep_kernel(
        // encoder args
        const float* __restrict__ x_b, const float* __restrict__ x_r,
        const float* __restrict__ W_b, const float* __restrict__ b_b,
        const float* __restrict__ W_r, const float* __restrict__ b_r,
        __half* __restrict__ h_b16, __half* __restrict__ h_r16,
        int NB, int NR, int encBlocks,
        // place-A args
        const int* __restrict__ src_rb, const int* __restrict__ dst_rb,
        const int* __restrict__ src_bb, const int* __restrict__ dst_bb,
        int* __restrict__ gcur1, int* __restrict__ bins1,
        int E_RB, int E_BB, int NSUP) {
    int t = threadIdx.x;

    if (blockIdx.x < encBlocks) {
        // ---------------- encoder part ----------------
        __shared__ float sWb[16][H];
        __shared__ float sWr8[8][H];
        __shared__ float sbb[H];
        __shared__ float sbr[H];
        for (int i = t; i < 16 * H; i += TPB) ((float*)sWb)[i] = W_b[i];
        for (int i = t; i < 8 * H; i += TPB) ((float*)sWr8)[i] = W_r[i];
        if (t < H) { sbb[t] = b_b[t]; sbr[t] = b_r[t]; }
        __syncthreads();

        long long node = (long long)blockIdx.x * TPB + t;
        if (node < NB) {
            const float4* px = (const float4*)(x_b + node * 16);
            float acc[H];
            #pragma unroll
            for (int j = 0; j < H; ++j) acc[j] = sbb[j];
            #pragma unroll
            for (int c = 0; c < 4; ++c) {
                float4 q = px[c];
                float xs[4] = {q.x, q.y, q.z, q.w};
                #pragma unroll
                for (int u = 0; u < 4; ++u) {
                    int k = c * 4 + u;
                    #pragma unroll
                    for (int j = 0; j < H; ++j)
                        acc[j] = fmaf(xs[u], sWb[k][j], acc[j]);
                }
            }
            __half2 o[H / 2];
            #pragma unroll
            for (int j2 = 0; j2 < H / 2; ++j2)
                o[j2] = __floats2half2_rn(fmaxf(acc[2 * j2], 0.0f), fmaxf(acc[2 * j2 + 1], 0.0f));
            float4* dst = (float4*)(h_b16 + node * H);
            const float4* src = (const float4*)o;
            dst[0] = src[0]; dst[1] = src[1]; dst[2] = src[2]; dst[3] = src[3];
        } else if (node < (long long)NB + NR) {
            long long m = node - NB;
            const float4* px = (const float4*)(x_r + m * 8);
            float acc[H];
            #pragma unroll
            for (int j = 0; j < H; ++j) acc[j] = sbr[j];
            #pragma unroll
            for (int c = 0; c < 2; ++c) {
                float4 q = px[c];
                float xs[4] = {q.x, q.y, q.z, q.w};
                #pragma unroll
                for (int u = 0; u < 4; ++u) {
                    int k = c * 4 + u;
                    #pragma unroll
                    for (int j = 0; j < H; ++j)
                        acc[j] = fmaf(xs[u], sWr8[k][j], acc[j]);
                }
            }
            __half2 o[H / 2];
            #pragma unroll
            for (int j2 = 0; j2 < H / 2; ++j2)
                o[j2] = __floats2half2_rn(fmaxf(acc[2 * j2], 0.0f), fmaxf(acc[2 * j2 + 1], 0.0f));
            float4* dst = (float4*)(h_r16 + m * H);
            const float4* src = (const float4*)o;
            dst[0] = src[0]; dst[1] = src[1]; dst[2] = src[2]; dst[3] = src[3];
        }
    } else {
        // ---------------- place-A: coarse radix into supers ----------------
        // packed1 = (src << 11) | (d & 2047); meta = (sup<<23)|(loc<<11)|(d&2047)
        __shared__ int lcnt[NSUPMAX];
        __shared__ int wbase[NSUPMAX];
        if (t < NSUPMAX) { lcnt[t] = 0; }
        __syncthreads();

        long long e0 = (long long)(blockIdx.x - encBlocks) * (TPB * EPT);
        long long EA = (long long)E_RB + E_BB;
        long long rb4 = (long long)(E_RB >> 2);
        int meta[EPT];

        // pass 1: histogram + meta (dst only, int4 loads)
        #pragma unroll
        for (int j = 0; j < EPT / 4; ++j) {
            long long i4 = (e0 >> 2) + (long long)j * TPB + t;
            long long eb = i4 << 2;
            int dd[4];
            if (eb + 3 < (long long)E_RB) {
                int4 dv = ((const int4*)dst_rb)[i4];
                dd[0] = dv.x; dd[1] = dv.y; dd[2] = dv.z; dd[3] = dv.w;
            } else if (eb >= (long long)E_RB && eb + 3 < EA) {
                int4 dv = ((const int4*)dst_bb)[i4 - rb4];
                dd[0] = dv.x + NB; dd[1] = dv.y + NB; dd[2] = dv.z + NB; dd[3] = dv.w + NB;
            } else {
                #pragma unroll
                for (int u = 0; u < 4; ++u) {
                    long long e = eb + u;
                    dd[u] = (e < E_RB) ? dst_rb[e] : (e < EA ? NB + dst_bb[e - E_RB] : -1);
                }
            }
            #pragma unroll
            for (int u = 0; u < 4; ++u) {
                if (dd[u] >= 0) {
                    int sup = dd[u] >> 11;
                    int loc = atomicAdd(&lcnt[sup], 1);
                    meta[j * 4 + u] = (sup << 23) | (loc << 11) | (dd[u] & 2047);
                } else meta[j * 4 + u] = -1;
            }
        }
        __syncthreads();

        // flush: one global atomic per (WG, nonempty super)
        if (t < NSUP) {
            int c = lcnt[t];
            wbase[t] = c ? (t * CAP1 + atomicAdd(&gcur1[t * 16], c)) : 0;
        }
        __syncthreads();

        // pass 2: re-read src (coalesced), write packed1 into super bins
        #pragma unroll
        for (int j = 0; j < EPT / 4; ++j) {
            long long i4 = (e0 >> 2) + (long long)j * TPB + t;
            long long eb = i4 << 2;
            int ss[4];
            if (eb + 3 < (long long)E_RB) {
                int4 sv = ((const int4*)src_rb)[i4];
                ss[0] = sv.x; ss[1] = sv.y; ss[2] = sv.z; ss[3] = sv.w;
            } else if (eb >= (long long)E_RB && eb + 3 < EA) {
                int4 sv = ((const int4*)src_bb)[i4 - rb4];
                ss[0] = sv.x; ss[1] = sv.y; ss[2] = sv.z; ss[3] = sv.w;
            } else {
                #pragma unroll
                for (int u = 0; u < 4; ++u) {
                    long long e = eb + u;
                    ss[u] = (e < E_RB) ? src_rb[e] : (e < EA ? (int)src_bb[e - E_RB] : 0);
                }
            }
            #pragma unroll
            for (int u = 0; u < 4; ++u) {
                int m = meta[j * 4 + u];
                if (m >= 0) {
                    int sup = (unsigned)m >> 23;
                    int loc = (m >> 11) & 0xFFF;
                    int gslot = wbase[sup] + loc;
                    if (gslot < (sup + 1) * CAP1)        // overflow guard (never fires)
                        bins1[gslot] = (ss[u] << 11) | (m & 2047);
                }
            }
        }
    }
}

// ---------------- place-B: fine radix within each super (coalesced) ------------------
// K2 WGs per super; each sub-bins its chunk into the super's 16 fine buckets.
__global__ void __launch_bounds__(TPB) placeB_kernel(
        const int* __restrict__ bins1, const int* __restrict__ gcur1,
        int* __restrict__ gcur2, int* __restrict__ bins, int NBUCK) {
    __shared__ int lcnt[16];
    __shared__ int wbase[16];
    __shared__ int lcur[16];
    int t = threadIdx.x;
    int sup = blockIdx.x / K2;
    int j   = blockIdx.x % K2;
    int n = gcur1[sup * 16];
    if (n > CAP1) n = CAP1;
    int chunk = (n + K2 - 1) / K2;
    int lo = j * chunk;
    int hi = lo + chunk; if (hi > n) hi = n;

    if (t < 16) lcnt[t] = 0;
    __syncthreads();

    const int* __restrict__ seg = bins1 + (long long)sup * CAP1;
    // pass 1: histogram over 16 fine buckets
    for (int i = lo + t; i < hi; i += TPB)
        atomicAdd(&lcnt[(seg[i] >> 7) & 15], 1);
    __syncthreads();

    if (t < 16) {
        int c = lcnt[t];
        int fb = sup * 16 + t;
        wbase[t] = (c && fb < NBUCK) ? (fb * CAP + atomicAdd(&gcur2[fb * 16], c)) : 0;
        lcur[t] = 0;
    }
    __syncthreads();

    // pass 2: re-read (L2-hot), scatter into fine bins (long runs -> coalesced)
    for (int i = lo + t; i < hi; i += TPB) {
        int p = seg[i];
        int f = (p >> 7) & 15;
        int loc = atomicAdd(&lcur[f], 1);
        int fb = sup * 16 + f;
        int gslot = wbase[f] + loc;
        if (gslot < (fb + 1) * CAP)              // overflow guard (never fires)
            bins[gslot] = ((p >> 11) << 7) | (p & 127);
    }
}

// ---------------- fused build+gather: int4 bins read, sort, unroll-8 gather ----------
__global__ void __launch_bounds__(TPB) buildgather_kernel(
        const __half* __restrict__ h_r16, const __half* __restrict__ h_b16,
        const int* __restrict__ bins, const int* __restrict__ gcur2,
        __half* __restrict__ mean16, int NB, int N2) {
    __shared__ int rawbuf[CAP];          // 8 KB
    __shared__ int srcbuf[CAP];          // 8 KB
    __shared__ int lcnt[SLOTS];
    __shared__ int lbase[SLOTS];
    __shared__ int lcur[SLOTS];
    __shared__ int tmp[SLOTS];
    int t = threadIdx.x;
    int b = blockIdx.x;
    int start = b * CAP;
    int n = gcur2[b * 16];
    if (n > CAP) n = CAP;

    if (t < SLOTS) lcnt[t] = 0;
    __syncthreads();

    // phase A: int4 read of bins into LDS + per-slot histogram
    {
        int n4 = n >> 2;
        const int4* bins4 = (const int4*)(bins + start);
        for (int i = t; i < n4; i += TPB) {
            int4 p = bins4[i];
            ((int4*)rawbuf)[i] = p;
            atomicAdd(&lcnt[p.x & 127], 1);
            atomicAdd(&lcnt[p.y & 127], 1);
            atomicAdd(&lcnt[p.z & 127], 1);
            atomicAdd(&lcnt[p.w & 127], 1);
        }
        for (int i = (n4 << 2) + t; i < n; i += TPB) {
            int packed = bins[start + i];
            rawbuf[i] = packed;
            atomicAdd(&lcnt[packed & 127], 1);
        }
    }
    __syncthreads();

    // phase B: exclusive scan of 128 slot counters
    if (t < SLOTS) tmp[t] = lcnt[t];
    __syncthreads();
    for (int off = 1; off < SLOTS; off <<= 1) {
        int x = (t >= off && t < SLOTS) ? tmp[t - off] : 0;
        __syncthreads();
        if (t < SLOTS) tmp[t] += x;
        __syncthreads();
    }
    if (t < SLOTS) { lbase[t] = tmp[t] - lcnt[t]; lcur[t] = tmp[t] - lcnt[t]; }
    __syncthreads();

    // phase C: LDS->LDS scatter, slot-sorted
    for (int i = t; i < n; i += TPB) {
        int packed = rawbuf[i];
        int slot = atomicAdd(&lcur[packed & 127], 1);
        srcbuf[slot] = packed >> 7;
    }
    __syncthreads();

    // phase D: gather; 16 groups of 16 lanes; lane owns channels {2l,2l+1}; 8/4/1 ILP
    int lane = t & 15, g = t >> 4;
    long long base_slot = (long long)b << 7;
    for (int sl = g; sl < SLOTS; sl += (TPB / 16)) {
        long long gd = base_slot + sl;
        if (gd >= N2) break;
        const __half* __restrict__ hs = (gd < NB) ? h_r16 : h_b16;
        int off = lbase[sl];
        int cnt = lcnt[sl];
        float ax = 0.0f, ay = 0.0f;
        int k = 0;
        for (; k + 8 <= cnt; k += 8) {
            int s[8];
            #pragma unroll
            for (int jj = 0; jj < 8; ++jj) s[jj] = srcbuf[off + k + jj];
            float2 f[8];
            #pragma unroll
            for (int jj = 0; jj < 8; ++jj)
                f[jj] = __half22float2(*(const __half2*)(hs + (long long)s[jj] * H + 2 * lane));
            #pragma unroll
            for (int jj = 0; jj < 8; ++jj) { ax += f[jj].x; ay += f[jj].y; }
        }
        if (k + 4 <= cnt) {
            int s[4];
            #pragma unroll
            for (int jj = 0; jj < 4; ++jj) s[jj] = srcbuf[off + k + jj];
            float2 f[4];
            #pragma unroll
            for (int jj = 0; jj < 4; ++jj)
                f[jj] = __half22float2(*(const __half2*)(hs + (long long)s[jj] * H + 2 * lane));
            #pragma unroll
            for (int jj = 0; jj < 4; ++jj) { ax += f[jj].x; ay += f[jj].y; }
            k += 4;
        }
        for (; k < cnt; ++k) {
            int s = srcbuf[off + k];
            float2 f = __half22float2(*(const __half2*)(hs + (long long)s * H + 2 * lane));
            ax += f.x; ay += f.y;
        }
        float inv = 1.0f / fmaxf((float)cnt, 1.0f);
        *(__half2*)(mean16 + gd * H + 2 * lane) = __floats2half2_rn(ax * inv, ay * inv);
    }
}

// ---------------- fused head (thread = node, fp16 inputs, W broadcast from LDS) ----------
__global__ void __launch_bounds__(TPB) head_kernel(
        const __half* __restrict__ h_b16,
        const __half* __restrict__ mean16,   // [2NB, H]
        const float* __restrict__ Wl_rb,
        const float* __restrict__ bl_rb,
        const float* __restrict__ Wl_bb,
        const float* __restrict__ bl_bb,
        const float* __restrict__ Wr_rb,
        const float* __restrict__ Wr_bb,
        const float* __restrict__ Wo,
        const float* __restrict__ bo,
        float* __restrict__ y, int N) {
    __shared__ float sWl_rb[H][H];
    __shared__ float sWl_bb[H][H];
    __shared__ float sWr[H][H];
    __shared__ float sbl[H];
    __shared__ float sWo[H];
    __shared__ float sbo;

    int t = threadIdx.x;
    for (int i = t; i < H * H; i += blockDim.x) {
        ((float*)sWl_rb)[i] = Wl_rb[i];
        ((float*)sWl_bb)[i] = Wl_bb[i];
        ((float*)sWr)[i]    = Wr_rb[i] + Wr_bb[i];
    }
    if (t < H) {
        sbl[t] = bl_rb[t] + bl_bb[t];
        sWo[t] = Wo[t];
    }
    if (t == 0) sbo = bo[0];
    __syncthreads();

    int node = blockIdx.x * TPB + t;
    if (node >= N) return;

    const float4* pr = (const float4*)(mean16 + (long long)node * H);
    const float4* pb = (const float4*)(mean16 + ((long long)N + node) * H);
    const float4* ph = (const float4*)(h_b16 + (long long)node * H);

    float acc[H];
    #pragma unroll
    for (int j = 0; j < H; ++j) acc[j] = sbl[j];

    #pragma unroll
    for (int c = 0; c < 4; ++c) {            // 8 k-values per chunk
        float4 qr = pr[c];
        float4 qb = pb[c];
        float4 qh = ph[c];
        const __half2* hr = (const __half2*)&qr;
        const __half2* hb = (const __half2*)&qb;
        const __half2* hh = (const __half2*)&qh;
        #pragma unroll
        for (int u = 0; u < 4; ++u) {
            float2 fr = __half22float2(hr[u]);
            float2 fb = __half22float2(hb[u]);
            float2 fh = __half22float2(hh[u]);
            int k0 = c * 8 + u * 2;
            #pragma unroll
            for (int j = 0; j < H; ++j) {
                acc[j] = fmaf(fr.x, sWl_rb[k0][j], acc[j]);
                acc[j] = fmaf(fb.x, sWl_bb[k0][j], acc[j]);
                acc[j] = fmaf(fh.x, sWr[k0][j], acc[j]);
                acc[j] = fmaf(fr.y, sWl_rb[k0 + 1][j], acc[j]);
                acc[j] = fmaf(fb.y, sWl_bb[k0 + 1][j], acc[j]);
                acc[j] = fmaf(fh.y, sWr[k0 + 1][j], acc[j]);
            }
        }
    }

    float out = 0.0f;
    #pragma unroll
    for (int j = 0; j < H; ++j)
        out = fmaf(fmaxf(acc[j], 0.0f), sWo[j], out);
    y[node] = out + sbo;
}

extern "C" void kernel_launch(void* const* d_in, const int* in_sizes, int n_in,
                              void* d_out, int out_size, void* d_ws, size_t ws_size,
                              hipStream_t stream) {
    const float* x_bridge = (const float*)d_in[0];
    const float* x_road   = (const float*)d_in[1];
    const int* src_rb = (const int*)d_in[4];
    const int* dst_rb = (const int*)d_in[5];
    const int* src_bb = (const int*)d_in[6];
    const int* dst_bb = (const int*)d_in[7];
    const float* W_enc_b = (const float*)d_in[8];
    const float* b_enc_b = (const float*)d_in[9];
    const float* W_enc_r = (const float*)d_in[10];
    const float* b_enc_r = (const float*)d_in[11];
    const float* Wl_rb = (const float*)d_in[15];
    const float* bl_rb = (const float*)d_in[16];
    const float* Wr_rb = (const float*)d_in[17];
    const float* Wl_bb = (const float*)d_in[18];
    const float* bl_bb = (const float*)d_in[19];
    const float* Wr_bb = (const float*)d_in[20];
    const float* Wo = (const float*)d_in[21];
    const float* bo = (const float*)d_in[22];
    float* y = (float*)d_out;

    const int NB = in_sizes[0] / 16;
    const int NR = in_sizes[1] / 8;
    const int E_RB = in_sizes[4];
    const int E_BB = in_sizes[6];
    const int N2 = 2 * NB;
    const long long E_ALL = (long long)E_RB + E_BB;
    const int NBUCK = (N2 + SLOTS - 1) / SLOTS;     // 1563
    const int NSUP  = (N2 + SUPB - 1) / SUPB;       // 98

    // Workspace layout (~56 MB)
    char* wp = (char*)d_ws;
    __half* h_r16  = (__half*)wp; wp += (size_t)NR * H * sizeof(__half);
    __half* h_b16  = (__half*)wp; wp += (size_t)NB * H * sizeof(__half);
    __half* mean16 = (__half*)wp; wp += (size_t)N2 * H * sizeof(__half);
    int* bins1 = (int*)wp;       wp += (size_t)NSUP * CAP1 * sizeof(int);
    int* bins  = (int*)wp;       wp += (size_t)NBUCK * CAP * sizeof(int);
    int* gcur1 = (int*)wp;       wp += (size_t)NSUP * 16 * sizeof(int);
    int* gcur2 = (int*)wp;       wp += (size_t)NBUCK * 16 * sizeof(int);

    // zero both cursor arrays (contiguous)
    hipMemsetAsync(gcur1, 0, (size_t)(NSUP + NBUCK) * 16 * sizeof(int), stream);

    long long nodes = (long long)NB + NR;
    int encBlocks = (int)((nodes + TPB - 1) / TPB);                      // 1172
    int placeBlocks = (int)((E_ALL + (TPB * EPT) - 1) / (TPB * EPT));    // 367
    prep_kernel<<<encBlocks + placeBlocks, TPB, 0, stream>>>(
        x_bridge, x_road, W_enc_b, b_enc_b, W_enc_r, b_enc_r,
        h_b16, h_r16, NB, NR, encBlocks,
        src_rb, dst_rb, src_bb, dst_bb, gcur1, bins1, E_RB, E_BB, NSUP);

    // fine radix within supers (coalesced writes)
    placeB_kernel<<<NSUP * K2, TPB, 0, stream>>>(bins1, gcur1, gcur2, bins, NBUCK);

    // fused per-bucket slot-sort (LDS) + gather -> mean16
    buildgather_kernel<<<NBUCK, TPB, 0, stream>>>(h_r16, h_b16, bins, gcur2,
                                                  mean16, NB, N2);

    // fused head
    head_kernel<<<(NB + TPB - 1) / TPB, TPB, 0, stream>>>(h_b16, mean16,
                                                  Wl_rb, bl_rb, Wl_bb, bl_bb,
                                                  Wr_rb, Wr_bb, Wo, bo, y, NB);
}

// Round 24
// 87.111 us; speedup vs baseline: 1.2223x; 1.0260x over previous
//
#include <hip/hip_runtime.h>
#include <hip/hip_fp16.h>

#define H 32
#define TPB 256
#define EPT 16            // edges per thread in place-A (4096 edges per WG, 367 WGs)
#define SLOTS 128         // dst slots per fine bucket
#define CAP 2048          // fine bucket capacity (rb-region mean 1280, +21 sigma)
#define SUPB 2048         // dst slots per super bucket (16 fine buckets)
#define CAP1 22528        // super capacity (rb-region mean 20480, +14 sigma)
#define K2 16             // WGs per super in pass B (1568 WGs)
#define NSUPMAX 128       // static bound (actual NSUP = 98)

// ---------------- prep: heterogeneous kernel -----------------------------------------
// Blocks [0, encBlocks): encoder (thread = node).
// Blocks [encBlocks, ...): place-A: radix-bin edges into 98 coarse supers.
// gcur1 must be zeroed before launch.
__global__ void __launch_bounds__(TPB) prep_kernel(
        // encoder args
        const float* __restrict__ x_b, const float* __restrict__ x_r,
        const float* __restrict__ W_b, const float* __restrict__ b_b,
        const float* __restrict__ W_r, const float* __restrict__ b_r,
        __half* __restrict__ h_b16, __half* __restrict__ h_r16,
        int NB, int NR, int encBlocks,
        // place-A args
        const int* __restrict__ src_rb, const int* __restrict__ dst_rb,
        const int* __restrict__ src_bb, const int* __restrict__ dst_bb,
        int* __restrict__ gcur1, int* __restrict__ bins1,
        int E_RB, int E_BB, int NSUP) {
    int t = threadIdx.x;

    if (blockIdx.x < encBlocks) {
        // ---------------- encoder part ----------------
        __shared__ float sWb[16][H];
        __shared__ float sWr8[8][H];
        __shared__ float sbb[H];
        __shared__ float sbr[H];
        for (int i = t; i < 16 * H; i += TPB) ((float*)sWb)[i] = W_b[i];
        for (int i = t; i < 8 * H; i += TPB) ((float*)sWr8)[i] = W_r[i];
        if (t < H) { sbb[t] = b_b[t]; sbr[t] = b_r[t]; }
        __syncthreads();

        long long node = (long long)blockIdx.x * TPB + t;
        if (node < NB) {
            const float4* px = (const float4*)(x_b + node * 16);
            float acc[H];
            #pragma unroll
            for (int j = 0; j < H; ++j) acc[j] = sbb[j];
            #pragma unroll
            for (int c = 0; c < 4; ++c) {
                float4 q = px[c];
                float xs[4] = {q.x, q.y, q.z, q.w};
                #pragma unroll
                for (int u = 0; u < 4; ++u) {
                    int k = c * 4 + u;
                    #pragma unroll
                    for (int j = 0; j < H; ++j)
                        acc[j] = fmaf(xs[u], sWb[k][j], acc[j]);
                }
            }
            __half2 o[H / 2];
            #pragma unroll
            for (int j2 = 0; j2 < H / 2; ++j2)
                o[j2] = __floats2half2_rn(fmaxf(acc[2 * j2], 0.0f), fmaxf(acc[2 * j2 + 1], 0.0f));
            float4* dst = (float4*)(h_b16 + node * H);
            const float4* src = (const float4*)o;
            dst[0] = src[0]; dst[1] = src[1]; dst[2] = src[2]; dst[3] = src[3];
        } else if (node < (long long)NB + NR) {
            long long m = node - NB;
            const float4* px = (const float4*)(x_r + m * 8);
            float acc[H];
            #pragma unroll
            for (int j = 0; j < H; ++j) acc[j] = sbr[j];
            #pragma unroll
            for (int c = 0; c < 2; ++c) {
                float4 q = px[c];
                float xs[4] = {q.x, q.y, q.z, q.w};
                #pragma unroll
                for (int u = 0; u < 4; ++u) {
                    int k = c * 4 + u;
                    #pragma unroll
                    for (int j = 0; j < H; ++j)
                        acc[j] = fmaf(xs[u], sWr8[k][j], acc[j]);
                }
            }
            __half2 o[H / 2];
            #pragma unroll
            for (int j2 = 0; j2 < H / 2; ++j2)
                o[j2] = __floats2half2_rn(fmaxf(acc[2 * j2], 0.0f), fmaxf(acc[2 * j2 + 1], 0.0f));
            float4* dst = (float4*)(h_r16 + m * H);
            const float4* src = (const float4*)o;
            dst[0] = src[0]; dst[1] = src[1]; dst[2] = src[2]; dst[3] = src[3];
        }
    } else {
        // ---------------- place-A: coarse radix into supers ----------------
        // packed1 = (src << 11) | (d & 2047); meta = (sup<<23)|(loc<<11)|(d&2047)
        __shared__ int lcnt[NSUPMAX];
        __shared__ int wbase[NSUPMAX];
        if (t < NSUPMAX) { lcnt[t] = 0; }
        __syncthreads();

        long long e0 = (long long)(blockIdx.x - encBlocks) * (TPB * EPT);
        long long EA = (long long)E_RB + E_BB;
        long long rb4 = (long long)(E_RB >> 2);
        int meta[EPT];

        // pass 1: histogram + meta (dst only, int4 loads)
        #pragma unroll
        for (int j = 0; j < EPT / 4; ++j) {
            long long i4 = (e0 >> 2) + (long long)j * TPB + t;
            long long eb = i4 << 2;
            int dd[4];
            if (eb + 3 < (long long)E_RB) {
                int4 dv = ((const int4*)dst_rb)[i4];
                dd[0] = dv.x; dd[1] = dv.y; dd[2] = dv.z; dd[3] = dv.w;
            } else if (eb >= (long long)E_RB && eb + 3 < EA) {
                int4 dv = ((const int4*)dst_bb)[i4 - rb4];
                dd[0] = dv.x + NB; dd[1] = dv.y + NB; dd[2] = dv.z + NB; dd[3] = dv.w + NB;
            } else {
                #pragma unroll
                for (int u = 0; u < 4; ++u) {
                    long long e = eb + u;
                    dd[u] = (e < E_RB) ? dst_rb[e] : (e < EA ? NB + dst_bb[e - E_RB] : -1);
                }
            }
            #pragma unroll
            for (int u = 0; u < 4; ++u) {
                if (dd[u] >= 0) {
                    int sup = dd[u] >> 11;
                    int loc = atomicAdd(&lcnt[sup], 1);
                    meta[j * 4 + u] = (sup << 23) | (loc << 11) | (dd[u] & 2047);
                } else meta[j * 4 + u] = -1;
            }
        }
        __syncthreads();

        // flush: one global atomic per (WG, nonempty super)
        if (t < NSUP) {
            int c = lcnt[t];
            wbase[t] = c ? (t * CAP1 + atomicAdd(&gcur1[t * 16], c)) : 0;
        }
        __syncthreads();

        // pass 2: re-read src (coalesced), write packed1 into super bins
        #pragma unroll
        for (int j = 0; j < EPT / 4; ++j) {
            long long i4 = (e0 >> 2) + (long long)j * TPB + t;
            long long eb = i4 << 2;
            int ss[4];
            if (eb + 3 < (long long)E_RB) {
                int4 sv = ((const int4*)src_rb)[i4];
                ss[0] = sv.x; ss[1] = sv.y; ss[2] = sv.z; ss[3] = sv.w;
            } else if (eb >= (long long)E_RB && eb + 3 < EA) {
                int4 sv = ((const int4*)src_bb)[i4 - rb4];
                ss[0] = sv.x; ss[1] = sv.y; ss[2] = sv.z; ss[3] = sv.w;
            } else {
                #pragma unroll
                for (int u = 0; u < 4; ++u) {
                    long long e = eb + u;
                    ss[u] = (e < E_RB) ? src_rb[e] : (e < EA ? (int)src_bb[e - E_RB] : 0);
                }
            }
            #pragma unroll
            for (int u = 0; u < 4; ++u) {
                int m = meta[j * 4 + u];
                if (m >= 0) {
                    int sup = (unsigned)m >> 23;
                    int loc = (m >> 11) & 0xFFF;
                    int gslot = wbase[sup] + loc;
                    if (gslot < (sup + 1) * CAP1)        // overflow guard (never fires)
                        bins1[gslot] = (ss[u] << 11) | (m & 2047);
                }
            }
        }
    }
}

// ---------------- place-B: fine radix within each super (coalesced) ------------------
// K2 WGs per super; each sub-bins its chunk into the super's 16 fine buckets.
__global__ void __launch_bounds__(TPB) placeB_kernel(
        const int* __restrict__ bins1, const int* __restrict__ gcur1,
        int* __restrict__ gcur2, int* __restrict__ bins, int NBUCK) {
    __shared__ int lcnt[16];
    __shared__ int wbase[16];
    __shared__ int lcur[16];
    int t = threadIdx.x;
    int sup = blockIdx.x / K2;
    int j   = blockIdx.x % K2;
    int n = gcur1[sup * 16];
    if (n > CAP1) n = CAP1;
    int chunk = (n + K2 - 1) / K2;
    int lo = j * chunk;
    int hi = lo + chunk; if (hi > n) hi = n;

    if (t < 16) lcnt[t] = 0;
    __syncthreads();

    const int* __restrict__ seg = bins1 + (long long)sup * CAP1;
    // pass 1: histogram over 16 fine buckets
    for (int i = lo + t; i < hi; i += TPB)
        atomicAdd(&lcnt[(seg[i] >> 7) & 15], 1);
    __syncthreads();

    if (t < 16) {
        int c = lcnt[t];
        int fb = sup * 16 + t;
        wbase[t] = (c && fb < NBUCK) ? (fb * CAP + atomicAdd(&gcur2[fb * 16], c)) : 0;
        lcur[t] = 0;
    }
    __syncthreads();

    // pass 2: re-read (L2-hot), scatter into fine bins (long runs -> coalesced)
    for (int i = lo + t; i < hi; i += TPB) {
        int p = seg[i];
        int f = (p >> 7) & 15;
        int loc = atomicAdd(&lcur[f], 1);
        int fb = sup * 16 + f;
        int gslot = wbase[f] + loc;
        if (gslot < (fb + 1) * CAP)              // overflow guard (never fires)
            bins[gslot] = ((p >> 11) << 7) | (p & 127);
    }
}

// ---------------- fused build+gather: int4 bins read, sort, unroll-8 gather ----------
__global__ void __launch_bounds__(TPB) buildgather_kernel(
        const __half* __restrict__ h_r16, const __half* __restrict__ h_b16,
        const int* __restrict__ bins, const int* __restrict__ gcur2,
        __half* __restrict__ mean16, int NB, int N2) {
    __shared__ int rawbuf[CAP];          // 8 KB
    __shared__ int srcbuf[CAP];          // 8 KB
    __shared__ int lcnt[SLOTS];
    __shared__ int lbase[SLOTS];
    __shared__ int lcur[SLOTS];
    __shared__ int tmp[SLOTS];
    int t = threadIdx.x;
    int b = blockIdx.x;
    int start = b * CAP;
    int n = gcur2[b * 16];
    if (n > CAP) n = CAP;

    if (t < SLOTS) lcnt[t] = 0;
    __syncthreads();

    // phase A: int4 read of bins into LDS + per-slot histogram
    {
        int n4 = n >> 2;
        const int4* bins4 = (const int4*)(bins + start);
        for (int i = t; i < n4; i += TPB) {
            int4 p = bins4[i];
            ((int4*)rawbuf)[i] = p;
            atomicAdd(&lcnt[p.x & 127], 1);
            atomicAdd(&lcnt[p.y & 127], 1);
            atomicAdd(&lcnt[p.z & 127], 1);
            atomicAdd(&lcnt[p.w & 127], 1);
        }
        for (int i = (n4 << 2) + t; i < n; i += TPB) {
            int packed = bins[start + i];
            rawbuf[i] = packed;
            atomicAdd(&lcnt[packed & 127], 1);
        }
    }
    __syncthreads();

    // phase B: exclusive scan of 128 slot counters
    if (t < SLOTS) tmp[t] = lcnt[t];
    __syncthreads();
    for (int off = 1; off < SLOTS; off <<= 1) {
        int x = (t >= off && t < SLOTS) ? tmp[t - off] : 0;
        __syncthreads();
        if (t < SLOTS) tmp[t] += x;
        __syncthreads();
    }
    if (t < SLOTS) { lbase[t] = tmp[t] - lcnt[t]; lcur[t] = tmp[t] - lcnt[t]; }
    __syncthreads();

    // phase C: LDS->LDS scatter, slot-sorted
    for (int i = t; i < n; i += TPB) {
        int packed = rawbuf[i];
        int slot = atomicAdd(&lcur[packed & 127], 1);
        srcbuf[slot] = packed >> 7;
    }
    __syncthreads();

    // phase D: gather; 16 groups of 16 lanes; lane owns channels {2l,2l+1}; 8/4/1 ILP
    int lane = t & 15, g = t >> 4;
    long long base_slot = (long long)b << 7;
    for (int sl = g; sl < SLOTS; sl += (TPB / 16)) {
        long long gd = base_slot + sl;
        if (gd >= N2) break;
        const __half* __restrict__ hs = (gd < NB) ? h_r16 : h_b16;
        int off = lbase[sl];
        int cnt = lcnt[sl];
        float ax = 0.0f, ay = 0.0f;
        int k = 0;
        for (; k + 8 <= cnt; k += 8) {
            int s[8];
            #pragma unroll
            for (int jj = 0; jj < 8; ++jj) s[jj] = srcbuf[off + k + jj];
            float2 f[8];
            #pragma unroll
            for (int jj = 0; jj < 8; ++jj)
                f[jj] = __half22float2(*(const __half2*)(hs + (long long)s[jj] * H + 2 * lane));
            #pragma unroll
            for (int jj = 0; jj < 8; ++jj) { ax += f[jj].x; ay += f[jj].y; }
        }
        if (k + 4 <= cnt) {
            int s[4];
            #pragma unroll
            for (int jj = 0; jj < 4; ++jj) s[jj] = srcbuf[off + k + jj];
            float2 f[4];
            #pragma unroll
            for (int jj = 0; jj < 4; ++jj)
                f[jj] = __half22float2(*(const __half2*)(hs + (long long)s[jj] * H + 2 * lane));
            #pragma unroll
            for (int jj = 0; jj < 4; ++jj) { ax += f[jj].x; ay += f[jj].y; }
            k += 4;
        }
        for (; k < cnt; ++k) {
            int s = srcbuf[off + k];
            float2 f = __half22float2(*(const __half2*)(hs + (long long)s * H + 2 * lane));
            ax += f.x; ay += f.y;
        }
        float inv = 1.0f / fmaxf((float)cnt, 1.0f);
        *(__half2*)(mean16 + gd * H + 2 * lane) = __floats2half2_rn(ax * inv, ay * inv);
    }
}

// ---------------- fused head (thread = node, fp16 inputs, W broadcast from LDS) ----------
__global__ void __launch_bounds__(TPB) head_kernel(
        const __half* __restrict__ h_b16,
        const __half* __restrict__ mean16,   // [2NB, H]
        const float* __restrict__ Wl_rb,
        const float* __restrict__ bl_rb,
        const float* __restrict__ Wl_bb,
        const float* __restrict__ bl_bb,
        const float* __restrict__ Wr_rb,
        const float* __restrict__ Wr_bb,
        const float* __restrict__ Wo,
        const float* __restrict__ bo,
        float* __restrict__ y, int N) {
    __shared__ float sWl_rb[H][H];
    __shared__ float sWl_bb[H][H];
    __shared__ float sWr[H][H];
    __shared__ float sbl[H];
    __shared__ float sWo[H];
    __shared__ float sbo;

    int t = threadIdx.x;
    for (int i = t; i < H * H; i += blockDim.x) {
        ((float*)sWl_rb)[i] = Wl_rb[i];
        ((float*)sWl_bb)[i] = Wl_bb[i];
        ((float*)sWr)[i]    = Wr_rb[i] + Wr_bb[i];
    }
    if (t < H) {
        sbl[t] = bl_rb[t] + bl_bb[t];
        sWo[t] = Wo[t];
    }
    if (t == 0) sbo = bo[0];
    __syncthreads();

    int node = blockIdx.x * TPB + t;
    if (node >= N) return;

    const float4* pr = (const float4*)(mean16 + (long long)node * H);
    const float4* pb = (const float4*)(mean16 + ((long long)N + node) * H);
    const float4* ph = (const float4*)(h_b16 + (long long)node * H);

    float acc[H];
    #pragma unroll
    for (int j = 0; j < H; ++j) acc[j] = sbl[j];

    #pragma unroll
    for (int c = 0; c < 4; ++c) {            // 8 k-values per chunk
        float4 qr = pr[c];
        float4 qb = pb[c];
        float4 qh = ph[c];
        const __half2* hr = (const __half2*)&qr;
        const __half2* hb = (const __half2*)&qb;
        const __half2* hh = (const __half2*)&qh;
        #pragma unroll
        for (int u = 0; u < 4; ++u) {
            float2 fr = __half22float2(hr[u]);
            float2 fb = __half22float2(hb[u]);
            float2 fh = __half22float2(hh[u]);
            int k0 = c * 8 + u * 2;
            #pragma unroll
            for (int j = 0; j < H; ++j) {
                acc[j] = fmaf(fr.x, sWl_rb[k0][j], acc[j]);
                acc[j] = fmaf(fb.x, sWl_bb[k0][j], acc[j]);
                acc[j] = fmaf(fh.x, sWr[k0][j], acc[j]);
                acc[j] = fmaf(fr.y, sWl_rb[k0 + 1][j], acc[j]);
                acc[j] = fmaf(fb.y, sWl_bb[k0 + 1][j], acc[j]);
                acc[j] = fmaf(fh.y, sWr[k0 + 1][j], acc[j]);
            }
        }
    }

    float out = 0.0f;
    #pragma unroll
    for (int j = 0; j < H; ++j)
        out = fmaf(fmaxf(acc[j], 0.0f), sWo[j], out);
    y[node] = out + sbo;
}

extern "C" void kernel_launch(void* const* d_in, const int* in_sizes, int n_in,
                              void* d_out, int out_size, void* d_ws, size_t ws_size,
                              hipStream_t stream) {
    const float* x_bridge = (const float*)d_in[0];
    const float* x_road   = (const float*)d_in[1];
    const int* src_rb = (const int*)d_in[4];
    const int* dst_rb = (const int*)d_in[5];
    const int* src_bb = (const int*)d_in[6];
    const int* dst_bb = (const int*)d_in[7];
    const float* W_enc_b = (const float*)d_in[8];
    const float* b_enc_b = (const float*)d_in[9];
    const float* W_enc_r = (const float*)d_in[10];
    const float* b_enc_r = (const float*)d_in[11];
    const float* Wl_rb = (const float*)d_in[15];
    const float* bl_rb = (const float*)d_in[16];
    const float* Wr_rb = (const float*)d_in[17];
    const float* Wl_bb = (const float*)d_in[18];
    const float* bl_bb = (const float*)d_in[19];
    const float* Wr_bb = (const float*)d_in[20];
    const float* Wo = (const float*)d_in[21];
    const float* bo = (const float*)d_in[22];
    float* y = (float*)d_out;

    const int NB = in_sizes[0] / 16;
    const int NR = in_sizes[1] / 8;
    const int E_RB = in_sizes[4];
    const int E_BB = in_sizes[6];
    const int N2 = 2 * NB;
    const long long E_ALL = (long long)E_RB + E_BB;
    const int NBUCK = (N2 + SLOTS - 1) / SLOTS;     // 1563
    const int NSUP  = (N2 + SUPB - 1) / SUPB;       // 98

    // Workspace layout (~56 MB)
    char* wp = (char*)d_ws;
    __half* h_r16  = (__half*)wp; wp += (size_t)NR * H * sizeof(__half);
    __half* h_b16  = (__half*)wp; wp += (size_t)NB * H * sizeof(__half);
    __half* mean16 = (__half*)wp; wp += (size_t)N2 * H * sizeof(__half);
    int* bins1 = (int*)wp;       wp += (size_t)NSUP * CAP1 * sizeof(int);
    int* bins  = (int*)wp;       wp += (size_t)NBUCK * CAP * sizeof(int);
    int* gcur1 = (int*)wp;       wp += (size_t)NSUP * 16 * sizeof(int);
    int* gcur2 = (int*)wp;       wp += (size_t)NBUCK * 16 * sizeof(int);

    // zero both cursor arrays (contiguous)
    hipMemsetAsync(gcur1, 0, (size_t)(NSUP + NBUCK) * 16 * sizeof(int), stream);

    long long nodes = (long long)NB + NR;
    int encBlocks = (int)((nodes + TPB - 1) / TPB);                      // 1172
    int placeBlocks = (int)((E_ALL + (TPB * EPT) - 1) / (TPB * EPT));    // 367
    prep_kernel<<<encBlocks + placeBlocks, TPB, 0, stream>>>(
        x_bridge, x_road, W_enc_b, b_enc_b, W_enc_r, b_enc_r,
        h_b16, h_r16, NB, NR, encBlocks,
        src_rb, dst_rb, src_bb, dst_bb, gcur1, bins1, E_RB, E_BB, NSUP);

    // fine radix within supers (coalesced writes)
    placeB_kernel<<<NSUP * K2, TPB, 0, stream>>>(bins1, gcur1, gcur2, bins, NBUCK);

    // fused per-bucket slot-sort (LDS) + gather -> mean16
    buildgather_kernel<<<NBUCK, TPB, 0, stream>>>(h_r16, h_b16, bins, gcur2,
                                                  mean16, NB, N2);

    // fused head
    head_kernel<<<(NB + TPB - 1) / TPB, TPB, 0, stream>>>(h_b16, mean16,
                                                  Wl_rb, bl_rb, Wl_bb, bl_bb,
                                                  Wr_rb, Wr_bb, Wo, bo, y, NB);
}